// Round 5
// baseline (863.814 us; speedup 1.0000x reference)
//
#include <hip/hip_runtime.h>
#include <stdint.h>
#include <stddef.h>

#define B_    8192
#define C_    512
#define F_    8
#define COUP_ 1024
#define NBL_  2
#define D1_   256
#define D2_   256

typedef __attribute__((ext_vector_type(8))) short   short8;
typedef __attribute__((ext_vector_type(4))) float   floatx4;
typedef __attribute__((ext_vector_type(8))) int     int8v;
typedef __attribute__((ext_vector_type(4))) int     int4v;

__device__ __forceinline__ unsigned short f2bf(float f) {
  unsigned int u = __float_as_uint(f);
  unsigned int r = (u + 0x7fffu + ((u >> 16) & 1u)) >> 16;
  return (unsigned short)r;
}

#if __has_builtin(__builtin_amdgcn_cvt_pk_fp8_f32)
__device__ __forceinline__ unsigned char f2fp8(float f) {
  return (unsigned char)(__builtin_amdgcn_cvt_pk_fp8_f32(f, f, 0, false) & 0xFF);
}
__device__ __forceinline__ unsigned int f2fp8x4(float4 v) {
  int r = __builtin_amdgcn_cvt_pk_fp8_f32(v.x, v.y, 0, false);
  r = __builtin_amdgcn_cvt_pk_fp8_f32(v.z, v.w, r, true);
  return (unsigned int)r;
}
#else
__device__ __forceinline__ unsigned char f2fp8(float f) {
  unsigned int fu = __float_as_uint(f);
  unsigned char s = (unsigned char)((fu >> 24) & 0x80u);
  float a = fabsf(f);
  if (!(a >= 0.015625f)) {
    int m = (int)rintf(a * 512.0f);
    return s | (unsigned char)m;
  }
  if (a > 448.0f) return s | 0x7E;
  unsigned int u = __float_as_uint(a);
  int e = (int)((u >> 23) & 0xFF) - 127;
  unsigned int mant = u & 0x7FFFFFu;
  unsigned int r = mant >> 20;
  unsigned int rest = mant & 0xFFFFFu;
  if (rest > 0x80000u || (rest == 0x80000u && (r & 1u))) r++;
  if (r == 8u) { r = 0u; e++; }
  if (e > 8) { e = 8; r = 7u; }
  return s | (unsigned char)(((unsigned)(e + 7) << 3) | r);
}
__device__ __forceinline__ unsigned int f2fp8x4(float4 v) {
  uchar4 o;
  o.x = f2fp8(v.x); o.y = f2fp8(v.y); o.z = f2fp8(v.z); o.w = f2fp8(v.w);
  return *(unsigned int*)&o;
}
#endif

__device__ __forceinline__ void gload_lds16(const void* g, void* l) {
  void* gnc = const_cast<void*>(g);
  __builtin_amdgcn_global_load_lds(
      (__attribute__((address_space(1))) void*)gnc,
      (__attribute__((address_space(3))) void*)l, 16, 0, 0);
}

// fp8 fragment read from the XOR-swizzled BK=128 tile:
// element (row r, chunk c) lives at (r>>3)*1024 + ((r&7)*8 + (c ^ (r&7)))*16
__device__ __forceinline__ int8v read_frag8(const unsigned char* lbase, int rr, int q) {
  const int j  = rr & 7;
  const int c0 = (2 * q) ^ j;
  const unsigned char* b = lbase + (rr >> 3) * 1024 + j * 128;
  int4v lo = *(const int4v*)(b + c0 * 16);
  int4v hi = *(const int4v*)(b + (c0 ^ 1) * 16);
  return __builtin_shufflevector(lo, hi, 0, 1, 2, 3, 4, 5, 6, 7);
}

// ---------------------------------------------------------------------------
// bf16 GEMM, 2-wave 128x64 tile — Wp: y = xb @ Wp^T (N=K=512)
// epilogue: LASTF=0: cols>=256 -> fp32 xst (y2 scratch); cols<256 -> fp8 x1
//           AND bf16 xb_next half1 (x1*scn+offn).
//           LASTF=1: all cols fp32 -> out; cols<256 also fp8 x1.
// ---------------------------------------------------------------------------
template<int LASTF>
__global__ __launch_bounds__(128, 2)
void gemm_wp(const unsigned short* __restrict__ A,
             const unsigned short* __restrict__ W,
             float* __restrict__ outF,
             unsigned char* __restrict__ outB,
             const float* __restrict__ scn, const float* __restrict__ offn,
             unsigned short* __restrict__ xbn,
             int M, int N, int K)
{
  __shared__ __align__(16) unsigned short lA[128 * 32];
  __shared__ __align__(16) unsigned short lB[64 * 32];
  const int tid  = threadIdx.x;
  const int wave = tid >> 6;
  const int lane = tid & 63;
  const int bm = blockIdx.y * 128;
  const int bn = blockIdx.x * 64;
  const int wm = wave * 64;

  floatx4 acc[4][4];
#pragma unroll
  for (int i = 0; i < 4; ++i)
#pragma unroll
    for (int j = 0; j < 4; ++j)
      acc[i][j] = (floatx4){0.f, 0.f, 0.f, 0.f};

  const int srow  = lane >> 2;
  const int skoff = (lane & 3) * 8;
  const unsigned short* ga = A + (size_t)(bm + wave * 64 + srow) * K + skoff;
  const unsigned short* gb = W + (size_t)(bn + wave * 32 + srow) * K + skoff;
  unsigned short* laB = &lA[(wave * 64) * 32];
  unsigned short* lbB = &lB[(wave * 32) * 32];
  const size_t rowstep = (size_t)16 * K;

  const int q8 = (lane >> 4) * 8;
  const int r  = lane & 15;

  for (int k0 = 0; k0 < K; k0 += 32) {
    if (k0) __syncthreads();
    gload_lds16(ga,               laB);
    gload_lds16(ga + rowstep,     laB + 16 * 32);
    gload_lds16(ga + 2 * rowstep, laB + 32 * 32);
    gload_lds16(ga + 3 * rowstep, laB + 48 * 32);
    gload_lds16(gb,               lbB);
    gload_lds16(gb + rowstep,     lbB + 16 * 32);
    ga += 32; gb += 32;
    __syncthreads();

    short8 af[4], bf[4];
#pragma unroll
    for (int t = 0; t < 4; ++t)
      af[t] = *(const short8*)&lA[(wm + t * 16 + r) * 32 + q8];
#pragma unroll
    for (int t = 0; t < 4; ++t)
      bf[t] = *(const short8*)&lB[(t * 16 + r) * 32 + q8];

#pragma unroll
    for (int i = 0; i < 4; ++i)
#pragma unroll
      for (int j = 0; j < 4; ++j)
        acc[i][j] = __builtin_amdgcn_mfma_f32_16x16x32_bf16(af[i], bf[j], acc[i][j], 0, 0, 0);
  }

  const int q4 = (lane >> 4) * 4;
  const int cc = lane & 15;
#pragma unroll
  for (int i = 0; i < 4; ++i) {
    const int row0 = bm + wm + i * 16 + q4;
#pragma unroll
    for (int j = 0; j < 4; ++j) {
      const int col = bn + j * 16 + cc;
#pragma unroll
      for (int rr = 0; rr < 4; ++rr) {
        const int row = row0 + rr;
        float v = acc[i][j][rr];
        if (LASTF) {
          outF[(size_t)row * 512 + col] = v;
        } else if (col >= D1_) {
          outF[(size_t)row * 512 + col] = v;
        }
        if (col < D1_) {
          outB[(size_t)row * D1_ + col] = f2fp8(v);
          if (!LASTF)
            xbn[(size_t)row * C_ + col] = f2bf(v * scn[col] + offn[col]);
        }
      }
    }
  }
}

// ---------------------------------------------------------------------------
// fp8 MX GEMM (unit scales), 4-wave 128x128 tile, BK=128.
// epilogue: relu(acc+bias) -> fp8 outB (ld N)
// ---------------------------------------------------------------------------
__global__ __launch_bounds__(256, 2)
void gemm_f8(const unsigned char* __restrict__ A,
             const unsigned char* __restrict__ W,
             const float* __restrict__ bias,
             unsigned char* __restrict__ outB,
             int M, int N, int K)
{
  __shared__ __align__(16) unsigned char lA[128 * 128];
  __shared__ __align__(16) unsigned char lB[128 * 128];
  const int tid  = threadIdx.x;
  const int wave = tid >> 6;
  const int lane = tid & 63;
  const int bm = blockIdx.y * 128;
  const int bn = blockIdx.x * 128;
  const int wm = (wave & 1) * 64;
  const int wn = (wave >> 1) * 64;

  floatx4 acc[4][4];
#pragma unroll
  for (int i = 0; i < 4; ++i)
#pragma unroll
    for (int j = 0; j < 4; ++j)
      acc[i][j] = (floatx4){0.f, 0.f, 0.f, 0.f};

  const int jj = lane >> 3;
  const int chunkoff = ((lane & 7) ^ jj) * 16;
  const unsigned char* gA = A + (size_t)(bm + jj) * K + chunkoff;
  const unsigned char* gB = W + (size_t)(bn + jj) * K + chunkoff;

  const int q = lane >> 4;
  const int r = lane & 15;

  for (int k0 = 0; k0 < K; k0 += 128) {
    if (k0) __syncthreads();
#pragma unroll
    for (int ii = 0; ii < 4; ++ii) {
      const int i = 4 * wave + ii;
      gload_lds16(gA + (size_t)(8 * i) * K + k0, &lA[i * 1024]);
      gload_lds16(gB + (size_t)(8 * i) * K + k0, &lB[i * 1024]);
    }
    __syncthreads();

    int8v af[4], bfv[4];
#pragma unroll
    for (int t = 0; t < 4; ++t) af[t]  = read_frag8(lA, wm + t * 16 + r, q);
#pragma unroll
    for (int t = 0; t < 4; ++t) bfv[t] = read_frag8(lB, wn + t * 16 + r, q);

#pragma unroll
    for (int i = 0; i < 4; ++i)
#pragma unroll
      for (int j = 0; j < 4; ++j)
        acc[i][j] = __builtin_amdgcn_mfma_scale_f32_16x16x128_f8f6f4(
            af[i], bfv[j], acc[i][j], 0, 0, 0, 0x7f7f7f7f, 0, 0x7f7f7f7f);
  }

  const int q4 = (lane >> 4) * 4;
  const int cc = lane & 15;
#pragma unroll
  for (int i = 0; i < 4; ++i) {
    const int row0 = bm + wm + i * 16 + q4;
#pragma unroll
    for (int j = 0; j < 4; ++j) {
      const int col = bn + wn + j * 16 + cc;
      const float bv = bias[col];
#pragma unroll
      for (int rr = 0; rr < 4; ++rr) {
        float v = acc[i][j][rr] + bv;
        v = v > 0.f ? v : 0.f;
        outB[(size_t)(row0 + rr) * N + col] = f2fp8(v);
      }
    }
  }
}

// ---------------------------------------------------------------------------
// fp8 MX GEMM + fused coupling, 2-wave 128x64(B-rows) tile.
// B-tile rows 0..31 = wo s-rows [32bnp..), rows 32..63 = wo t-rows [256+32bnp..).
// Epilogue: sa=0.1(acc_s+bo_s), ta=0.1(acc_t+bo_t); s=2tanh(sa);
//   x2n = xst[row,256+cp]*exp(s)+ta;
//   LASTF=0: xb_next[row,256+cp]=bf16(x2n*scn+offn);  LASTF=1: out[row,256+cp]=x2n
//   ldpart[bnp*B+row] += sum_cp s   (single writer, accumulated over f)
// ---------------------------------------------------------------------------
template<int LASTF>
__global__ __launch_bounds__(128, 2)
void gemm_wo_couple(const unsigned char* __restrict__ A,
                    const unsigned char* __restrict__ W,
                    const float* __restrict__ bias,
                    const float* __restrict__ xst,
                    float* __restrict__ outF,
                    const float* __restrict__ scn, const float* __restrict__ offn,
                    unsigned short* __restrict__ xbn,
                    float* __restrict__ ldpart,
                    int M, int K)
{
  __shared__ __align__(16) unsigned char lA[128 * 128];
  __shared__ __align__(16) unsigned char lB[64 * 128];
  const int tid  = threadIdx.x;
  const int wave = tid >> 6;
  const int lane = tid & 63;
  const int bm  = blockIdx.y * 128;
  const int bnp = blockIdx.x;            // col-pair group: cols [32bnp, 32bnp+32)
  const int wm  = wave * 64;

  floatx4 acc[4][4];
#pragma unroll
  for (int i = 0; i < 4; ++i)
#pragma unroll
    for (int j = 0; j < 4; ++j)
      acc[i][j] = (floatx4){0.f, 0.f, 0.f, 0.f};

  const int jj = lane >> 3;
  const int chunkoff = ((lane & 7) ^ jj) * 16;
  const unsigned char* gA = A + (size_t)(bm + jj) * K + chunkoff;
  // wave 0 stages s-rows (B-tile rows 0..31), wave 1 stages t-rows (32..63)
  const unsigned char* gB =
      W + (size_t)((wave ? 256 : 0) + 32 * bnp + jj) * K + chunkoff;

  const int q = lane >> 4;
  const int r = lane & 15;

  for (int k0 = 0; k0 < K; k0 += 128) {
    if (k0) __syncthreads();
#pragma unroll
    for (int ii = 0; ii < 8; ++ii) {     // A: 16 insts / 2 waves
      const int i = 8 * wave + ii;
      gload_lds16(gA + (size_t)(8 * i) * K + k0, &lA[i * 1024]);
    }
#pragma unroll
    for (int ii = 0; ii < 4; ++ii) {     // B: 8 insts / 2 waves
      gload_lds16(gB + (size_t)(8 * ii) * K + k0, &lB[(4 * wave + ii) * 1024]);
    }
    __syncthreads();

    int8v af[4], bfv[4];
#pragma unroll
    for (int t = 0; t < 4; ++t) af[t]  = read_frag8(lA, wm + t * 16 + r, q);
#pragma unroll
    for (int t = 0; t < 4; ++t) bfv[t] = read_frag8(lB, t * 16 + r, q);

#pragma unroll
    for (int i = 0; i < 4; ++i)
#pragma unroll
      for (int j = 0; j < 4; ++j)
        acc[i][j] = __builtin_amdgcn_mfma_scale_f32_16x16x128_f8f6f4(
            af[i], bfv[j], acc[i][j], 0, 0, 0, 0x7f7f7f7f, 0, 0x7f7f7f7f);
  }

  const int q4 = (lane >> 4) * 4;
  const int cc = lane & 15;
  float ssum[4][4];
#pragma unroll
  for (int i = 0; i < 4; ++i)
#pragma unroll
    for (int rr = 0; rr < 4; ++rr) ssum[i][rr] = 0.f;

#pragma unroll
  for (int i = 0; i < 4; ++i) {
    const int row0 = bm + wm + i * 16 + q4;
#pragma unroll
    for (int jjp = 0; jjp < 2; ++jjp) {
      const int cp = 32 * bnp + jjp * 16 + cc;    // a-col of s; t at cp+256
      const float bs = bias[cp];
      const float bt = bias[256 + cp];
#pragma unroll
      for (int rr = 0; rr < 4; ++rr) {
        const int row = row0 + rr;
        float sa = 0.1f * (acc[i][jjp][rr] + bs);
        float ta = 0.1f * (acc[i][jjp + 2][rr] + bt);
        float s  = 2.0f * tanhf(sa);
        float x2n = xst[(size_t)row * 512 + 256 + cp] * expf(s) + ta;
        if (LASTF) {
          outF[(size_t)row * 512 + 256 + cp] = x2n;
        } else {
          xbn[(size_t)row * C_ + D1_ + cp] = f2bf(x2n * scn[D1_ + cp] + offn[D1_ + cp]);
        }
        ssum[i][rr] += s;
      }
    }
  }

  // reduce ssum over the 16 cc-lanes; lane cc==0 owns the row
#pragma unroll
  for (int i = 0; i < 4; ++i)
#pragma unroll
    for (int rr = 0; rr < 4; ++rr) {
      float v = ssum[i][rr];
#pragma unroll
      for (int m = 1; m < 16; m <<= 1) v += __shfl_xor(v, m, 64);
      if (cc == 0) {
        const int row = bm + wm + i * 16 + q4 + rr;
        ldpart[(size_t)bnp * B_ + row] += v;
      }
    }
}

// scale[f][c] = 0.2*softplus(0.5*g); sumlog[f] = sum_c log(scale)
__global__ void scale_kernel(const float* __restrict__ g, float* __restrict__ sc,
                             float* __restrict__ sumlog) {
  const int f = blockIdx.x, t = threadIdx.x;
  __shared__ float red[256];
  float part = 0.f;
  for (int c = t; c < C_; c += 256) {
    float x  = 0.5f * g[f * C_ + c];
    float sp = log1pf(expf(x));
    float s  = 0.2f * sp;
    sc[f * C_ + c] = s;
    part += logf(s);
  }
  red[t] = part;
  __syncthreads();
  for (int o = 128; o > 0; o >>= 1) {
    if (t < o) red[t] += red[t + o];
    __syncthreads();
  }
  if (t == 0) sumlog[f] = red[0];
}

// weights: region 0 (Wp) -> bf16; regions 1-3 (w0, wh, wo) -> fp8 (HW cvt)
__global__ void cvt4_kernel(const float* __restrict__ s0, unsigned short* __restrict__ d0, int n0,
                            const float* __restrict__ s1, unsigned char* __restrict__ d1, int n1,
                            const float* __restrict__ s2, unsigned char* __restrict__ d2, int n2,
                            const float* __restrict__ s3, unsigned char* __restrict__ d3, int n3) {
  const int total4 = (n0 + n1 + n2 + n3) >> 2;
  for (int i = blockIdx.x * blockDim.x + threadIdx.x; i < total4;
       i += gridDim.x * blockDim.x) {
    int idx = i << 2;
    if (idx < n0) {
      float4 v = *(const float4*)(s0 + idx);
      ushort4 o;
      o.x = f2bf(v.x); o.y = f2bf(v.y); o.z = f2bf(v.z); o.w = f2bf(v.w);
      *(ushort4*)(d0 + idx) = o;
    } else {
      const float* s; unsigned char* d; int off;
      if (idx < n0 + n1)           { s = s1; d = d1; off = idx - n0; }
      else if (idx < n0 + n1 + n2) { s = s2; d = d2; off = idx - n0 - n1; }
      else                         { s = s3; d = d3; off = idx - n0 - n1 - n2; }
      *(unsigned int*)(d + off) = f2fp8x4(*(const float4*)(s + off));
    }
  }
}

// f=0: xb = bf16(z0*scale + off); also zero ldpart (8*B floats)
__global__ void prewp_kernel(const float* __restrict__ x, const float* __restrict__ sc,
                             const float* __restrict__ off, unsigned short* __restrict__ xb,
                             float* __restrict__ ldpart) {
  int i = blockIdx.x * blockDim.x + threadIdx.x;
  if (i < (8 * B_) / 4) *(float4*)(ldpart + i * 4) = (float4){0.f, 0.f, 0.f, 0.f};
  if (i >= (B_ * C_) / 4) return;
  int idx = i << 2;
  int c = idx & (C_ - 1);
  float4 v = *(const float4*)(x + idx);
  float4 s = *(const float4*)(sc + c);
  float4 o = *(const float4*)(off + c);
  ushort4 r;
  r.x = f2bf(v.x * s.x + o.x);
  r.y = f2bf(v.y * s.y + o.y);
  r.z = f2bf(v.z * s.z + o.z);
  r.w = f2bf(v.w * s.w + o.w);
  *(ushort4*)(xb + idx) = r;
}

// out_ld[row] = sum_nb ldpart[nb][row] + sum_f sumlog[f]
__global__ void final_ld_kernel(const float* __restrict__ ldpart,
                                const float* __restrict__ sumlog,
                                float* __restrict__ ldout) {
  int row = blockIdx.x * blockDim.x + threadIdx.x;
  if (row >= B_) return;
  float t = 0.f;
#pragma unroll
  for (int f = 0; f < F_; ++f) t += sumlog[f];
  float v = 0.f;
#pragma unroll
  for (int nb = 0; nb < 8; ++nb) v += ldpart[(size_t)nb * B_ + row];
  ldout[row] = v + t;
}

extern "C" void kernel_launch(void* const* d_in, const int* in_sizes, int n_in,
                              void* d_out, int out_size, void* d_ws, size_t ws_size,
                              hipStream_t stream) {
  const float* z0  = (const float*)d_in[0];
  const float* Wp  = (const float*)d_in[1];
  const float* g   = (const float*)d_in[2];
  const float* off = (const float*)d_in[3];
  const float* w0  = (const float*)d_in[4];
  const float* b0  = (const float*)d_in[5];
  const float* wh  = (const float*)d_in[6];
  const float* bh  = (const float*)d_in[7];
  const float* wo  = (const float*)d_in[8];
  const float* bo  = (const float*)d_in[9];
  float* out = (float*)d_out;

  char* ws = (char*)d_ws;
  size_t p = 0;
  auto alloc = [&](size_t bytes) -> void* {
    p = (p + 255) & ~(size_t)255;
    void* r = ws + p;
    p += bytes;
    return r;
  };
  float* sc           = (float*)alloc((size_t)F_ * C_ * 4);
  float* sumlog       = (float*)alloc((size_t)F_ * 4);
  float* ldpart       = (float*)alloc((size_t)8 * B_ * 4);
  float* xst          = (float*)alloc((size_t)B_ * C_ * 4);
  unsigned short* xbA = (unsigned short*)alloc((size_t)B_ * C_ * 2);
  unsigned short* xbB = (unsigned short*)alloc((size_t)B_ * C_ * 2);
  unsigned char* x1f8 = (unsigned char*)alloc((size_t)B_ * D1_);
  unsigned char* h1f8 = (unsigned char*)alloc((size_t)B_ * COUP_);
  unsigned char* h2f8 = (unsigned char*)alloc((size_t)B_ * COUP_);
  unsigned short* wpb = (unsigned short*)alloc((size_t)F_ * C_ * C_ * 2);
  unsigned char* w0f8 = (unsigned char*)alloc((size_t)F_ * COUP_ * D1_);
  unsigned char* whf8 = (unsigned char*)alloc((size_t)F_ * NBL_ * COUP_ * COUP_);
  unsigned char* wof8 = (unsigned char*)alloc((size_t)F_ * 2 * D2_ * COUP_);
  (void)ws_size; (void)in_sizes; (void)n_in; (void)out_size;

  scale_kernel<<<F_, 256, 0, stream>>>(g, sc, sumlog);

  cvt4_kernel<<<2048, 256, 0, stream>>>(
      Wp, wpb, F_ * C_ * C_,
      w0, w0f8, F_ * COUP_ * D1_,
      wh, whf8, F_ * NBL_ * COUP_ * COUP_,
      wo, wof8, F_ * 2 * D2_ * COUP_);

  prewp_kernel<<<(B_ * C_ / 4) / 256, 256, 0, stream>>>(z0, sc, off, xbA, ldpart);

  for (int f = 0; f < F_; ++f) {
    const int last = (f == F_ - 1);
    unsigned short* xbc = (f & 1) ? xbB : xbA;
    unsigned short* xbn = (f & 1) ? xbA : xbB;
    const float* scn  = sc  + (size_t)(f + 1) * C_;
    const float* offn = off + (size_t)(f + 1) * C_;

    if (!last) {
      gemm_wp<0><<<dim3(8, 64), 128, 0, stream>>>(
          xbc, wpb + (size_t)f * C_ * C_, xst, x1f8, scn, offn, xbn, B_, 512, 512);
    } else {
      gemm_wp<1><<<dim3(8, 64), 128, 0, stream>>>(
          xbc, wpb + (size_t)f * C_ * C_, out, x1f8, nullptr, nullptr, nullptr,
          B_, 512, 512);
    }

    gemm_f8<<<dim3(8, 64), 256, 0, stream>>>(
        x1f8, w0f8 + (size_t)f * COUP_ * D1_, b0 + (size_t)f * COUP_,
        h1f8, B_, COUP_, D1_);

    gemm_f8<<<dim3(8, 64), 256, 0, stream>>>(
        h1f8, whf8 + (size_t)(f * NBL_) * COUP_ * COUP_,
        bh + (size_t)(f * NBL_ + 0) * COUP_, h2f8, B_, COUP_, COUP_);

    gemm_f8<<<dim3(8, 64), 256, 0, stream>>>(
        h2f8, whf8 + (size_t)(f * NBL_ + 1) * COUP_ * COUP_,
        bh + (size_t)(f * NBL_ + 1) * COUP_, h1f8, B_, COUP_, COUP_);

    if (!last) {
      gemm_wo_couple<0><<<dim3(8, 64), 128, 0, stream>>>(
          h1f8, wof8 + (size_t)f * 2 * D2_ * COUP_, bo + (size_t)f * 2 * D2_,
          last ? out : xst, nullptr, scn, offn, xbn, ldpart, B_, COUP_);
    } else {
      gemm_wo_couple<1><<<dim3(8, 64), 128, 0, stream>>>(
          h1f8, wof8 + (size_t)f * 2 * D2_ * COUP_, bo + (size_t)f * 2 * D2_,
          out, out, nullptr, nullptr, nullptr, ldpart, B_, COUP_);
    }
  }

  final_ld_kernel<<<B_ / 256, 256, 0, stream>>>(ldpart, sumlog, out + (size_t)B_ * C_);
}

// Round 6
// 794.114 us; speedup vs baseline: 1.0878x; 1.0878x over previous
//
#include <hip/hip_runtime.h>
#include <stdint.h>
#include <stddef.h>

#define B_    8192
#define C_    512
#define F_    8
#define COUP_ 1024
#define NBL_  2
#define D1_   256
#define D2_   256

typedef __attribute__((ext_vector_type(8))) short   short8;
typedef __attribute__((ext_vector_type(4))) float   floatx4;
typedef __attribute__((ext_vector_type(8))) int     int8v;
typedef __attribute__((ext_vector_type(4))) int     int4v;

__device__ __forceinline__ unsigned short f2bf(float f) {
  unsigned int u = __float_as_uint(f);
  unsigned int r = (u + 0x7fffu + ((u >> 16) & 1u)) >> 16;
  return (unsigned short)r;
}

#if __has_builtin(__builtin_amdgcn_cvt_pk_fp8_f32)
__device__ __forceinline__ unsigned char f2fp8(float f) {
  return (unsigned char)(__builtin_amdgcn_cvt_pk_fp8_f32(f, f, 0, false) & 0xFF);
}
__device__ __forceinline__ unsigned int f2fp8x4(float4 v) {
  int r = __builtin_amdgcn_cvt_pk_fp8_f32(v.x, v.y, 0, false);
  r = __builtin_amdgcn_cvt_pk_fp8_f32(v.z, v.w, r, true);
  return (unsigned int)r;
}
#else
__device__ __forceinline__ unsigned char f2fp8(float f) {
  unsigned int fu = __float_as_uint(f);
  unsigned char s = (unsigned char)((fu >> 24) & 0x80u);
  float a = fabsf(f);
  if (!(a >= 0.015625f)) {
    int m = (int)rintf(a * 512.0f);
    return s | (unsigned char)m;
  }
  if (a > 448.0f) return s | 0x7E;
  unsigned int u = __float_as_uint(a);
  int e = (int)((u >> 23) & 0xFF) - 127;
  unsigned int mant = u & 0x7FFFFFu;
  unsigned int r = mant >> 20;
  unsigned int rest = mant & 0xFFFFFu;
  if (rest > 0x80000u || (rest == 0x80000u && (r & 1u))) r++;
  if (r == 8u) { r = 0u; e++; }
  if (e > 8) { e = 8; r = 7u; }
  return s | (unsigned char)(((unsigned)(e + 7) << 3) | r);
}
__device__ __forceinline__ unsigned int f2fp8x4(float4 v) {
  uchar4 o;
  o.x = f2fp8(v.x); o.y = f2fp8(v.y); o.z = f2fp8(v.z); o.w = f2fp8(v.w);
  return *(unsigned int*)&o;
}
#endif

__device__ __forceinline__ void gload_lds16(const void* g, void* l) {
  void* gnc = const_cast<void*>(g);
  __builtin_amdgcn_global_load_lds(
      (__attribute__((address_space(1))) void*)gnc,
      (__attribute__((address_space(3))) void*)l, 16, 0, 0);
}

// XCD-aware swizzle for (8, 64) grids. Round-robin XCD assignment gives
// XCD = L % 8; we map so each XCD gets 8 row-strips x all 8 col-blocks ->
// A-strip reads dedupe in that XCD's private L2 (8x HBM fetch reduction).
__device__ __forceinline__ void swz8x64(int& col, int& rowstrip) {
  const int L = blockIdx.x + (blockIdx.y << 3);
  const int xcd = L & 7;
  const int slot = L >> 3;
  col = slot & 7;
  rowstrip = ((slot >> 3) << 3) + xcd;
}

// fp8 fragment read from the XOR-swizzled BK=128 tile:
// element (row r, chunk c) lives at (r>>3)*1024 + ((r&7)*8 + (c ^ (r&7)))*16
__device__ __forceinline__ int8v read_frag8(const unsigned char* lbase, int rr, int q) {
  const int j  = rr & 7;
  const int c0 = (2 * q) ^ j;
  const unsigned char* b = lbase + (rr >> 3) * 1024 + j * 128;
  int4v lo = *(const int4v*)(b + c0 * 16);
  int4v hi = *(const int4v*)(b + (c0 ^ 1) * 16);
  return __builtin_shufflevector(lo, hi, 0, 1, 2, 3, 4, 5, 6, 7);
}

// ---------------------------------------------------------------------------
// bf16 GEMM, 2-wave 128x64 tile — Wp: y = xb @ Wp^T (N=K=512)
// ---------------------------------------------------------------------------
template<int LASTF>
__global__ __launch_bounds__(128, 2)
void gemm_wp(const unsigned short* __restrict__ A,
             const unsigned short* __restrict__ W,
             float* __restrict__ outF,
             unsigned char* __restrict__ outB,
             const float* __restrict__ scn, const float* __restrict__ offn,
             unsigned short* __restrict__ xbn,
             int M, int N, int K)
{
  __shared__ __align__(16) unsigned short lA[128 * 32];
  __shared__ __align__(16) unsigned short lB[64 * 32];
  const int tid  = threadIdx.x;
  const int wave = tid >> 6;
  const int lane = tid & 63;
  int colb, rowb;
  swz8x64(colb, rowb);
  const int bm = rowb * 128;
  const int bn = colb * 64;
  const int wm = wave * 64;

  floatx4 acc[4][4];
#pragma unroll
  for (int i = 0; i < 4; ++i)
#pragma unroll
    for (int j = 0; j < 4; ++j)
      acc[i][j] = (floatx4){0.f, 0.f, 0.f, 0.f};

  const int srow  = lane >> 2;
  const int skoff = (lane & 3) * 8;
  const unsigned short* ga = A + (size_t)(bm + wave * 64 + srow) * K + skoff;
  const unsigned short* gb = W + (size_t)(bn + wave * 32 + srow) * K + skoff;
  unsigned short* laB = &lA[(wave * 64) * 32];
  unsigned short* lbB = &lB[(wave * 32) * 32];
  const size_t rowstep = (size_t)16 * K;

  const int q8 = (lane >> 4) * 8;
  const int r  = lane & 15;

  for (int k0 = 0; k0 < K; k0 += 32) {
    if (k0) __syncthreads();
    gload_lds16(ga,               laB);
    gload_lds16(ga + rowstep,     laB + 16 * 32);
    gload_lds16(ga + 2 * rowstep, laB + 32 * 32);
    gload_lds16(ga + 3 * rowstep, laB + 48 * 32);
    gload_lds16(gb,               lbB);
    gload_lds16(gb + rowstep,     lbB + 16 * 32);
    ga += 32; gb += 32;
    __syncthreads();

    short8 af[4], bf[4];
#pragma unroll
    for (int t = 0; t < 4; ++t)
      af[t] = *(const short8*)&lA[(wm + t * 16 + r) * 32 + q8];
#pragma unroll
    for (int t = 0; t < 4; ++t)
      bf[t] = *(const short8*)&lB[(t * 16 + r) * 32 + q8];

#pragma unroll
    for (int i = 0; i < 4; ++i)
#pragma unroll
      for (int j = 0; j < 4; ++j)
        acc[i][j] = __builtin_amdgcn_mfma_f32_16x16x32_bf16(af[i], bf[j], acc[i][j], 0, 0, 0);
  }

  const int q4 = (lane >> 4) * 4;
  const int cc = lane & 15;
#pragma unroll
  for (int i = 0; i < 4; ++i) {
    const int row0 = bm + wm + i * 16 + q4;
#pragma unroll
    for (int j = 0; j < 4; ++j) {
      const int col = bn + j * 16 + cc;
#pragma unroll
      for (int rr = 0; rr < 4; ++rr) {
        const int row = row0 + rr;
        float v = acc[i][j][rr];
        if (LASTF) {
          outF[(size_t)row * 512 + col] = v;
        } else if (col >= D1_) {
          outF[(size_t)row * 512 + col] = v;
        }
        if (col < D1_) {
          outB[(size_t)row * D1_ + col] = f2fp8(v);
          if (!LASTF)
            xbn[(size_t)row * C_ + col] = f2bf(v * scn[col] + offn[col]);
        }
      }
    }
  }
}

// ---------------------------------------------------------------------------
// fp8 MX GEMM (unit scales), 4-wave 128x128 tile, BK=128.
// epilogue: relu(acc+bias) -> fp8 outB (ld N)
// ---------------------------------------------------------------------------
__global__ __launch_bounds__(256, 2)
void gemm_f8(const unsigned char* __restrict__ A,
             const unsigned char* __restrict__ W,
             const float* __restrict__ bias,
             unsigned char* __restrict__ outB,
             int M, int N, int K)
{
  __shared__ __align__(16) unsigned char lA[128 * 128];
  __shared__ __align__(16) unsigned char lB[128 * 128];
  const int tid  = threadIdx.x;
  const int wave = tid >> 6;
  const int lane = tid & 63;
  int colb, rowb;
  swz8x64(colb, rowb);
  const int bm = rowb * 128;
  const int bn = colb * 128;
  const int wm = (wave & 1) * 64;
  const int wn = (wave >> 1) * 64;

  floatx4 acc[4][4];
#pragma unroll
  for (int i = 0; i < 4; ++i)
#pragma unroll
    for (int j = 0; j < 4; ++j)
      acc[i][j] = (floatx4){0.f, 0.f, 0.f, 0.f};

  const int jj = lane >> 3;
  const int chunkoff = ((lane & 7) ^ jj) * 16;
  const unsigned char* gA = A + (size_t)(bm + jj) * K + chunkoff;
  const unsigned char* gB = W + (size_t)(bn + jj) * K + chunkoff;

  const int q = lane >> 4;
  const int r = lane & 15;

  for (int k0 = 0; k0 < K; k0 += 128) {
    if (k0) __syncthreads();
#pragma unroll
    for (int ii = 0; ii < 4; ++ii) {
      const int i = 4 * wave + ii;
      gload_lds16(gA + (size_t)(8 * i) * K + k0, &lA[i * 1024]);
      gload_lds16(gB + (size_t)(8 * i) * K + k0, &lB[i * 1024]);
    }
    __syncthreads();

    int8v af[4], bfv[4];
#pragma unroll
    for (int t = 0; t < 4; ++t) af[t]  = read_frag8(lA, wm + t * 16 + r, q);
#pragma unroll
    for (int t = 0; t < 4; ++t) bfv[t] = read_frag8(lB, wn + t * 16 + r, q);

#pragma unroll
    for (int i = 0; i < 4; ++i)
#pragma unroll
      for (int j = 0; j < 4; ++j)
        acc[i][j] = __builtin_amdgcn_mfma_scale_f32_16x16x128_f8f6f4(
            af[i], bfv[j], acc[i][j], 0, 0, 0, 0x7f7f7f7f, 0, 0x7f7f7f7f);
  }

  const int q4 = (lane >> 4) * 4;
  const int cc = lane & 15;
#pragma unroll
  for (int i = 0; i < 4; ++i) {
    const int row0 = bm + wm + i * 16 + q4;
#pragma unroll
    for (int j = 0; j < 4; ++j) {
      const int col = bn + wn + j * 16 + cc;
      const float bv = bias[col];
#pragma unroll
      for (int rr = 0; rr < 4; ++rr) {
        float v = acc[i][j][rr] + bv;
        v = v > 0.f ? v : 0.f;
        outB[(size_t)(row0 + rr) * N + col] = f2fp8(v);
      }
    }
  }
}

// ---------------------------------------------------------------------------
// fp8 MX GEMM + fused coupling, 2-wave 128x64(B-rows) tile.
// ---------------------------------------------------------------------------
template<int LASTF>
__global__ __launch_bounds__(128, 2)
void gemm_wo_couple(const unsigned char* __restrict__ A,
                    const unsigned char* __restrict__ W,
                    const float* __restrict__ bias,
                    const float* __restrict__ xst,
                    float* __restrict__ outF,
                    const float* __restrict__ scn, const float* __restrict__ offn,
                    unsigned short* __restrict__ xbn,
                    float* __restrict__ ldpart,
                    int M, int K)
{
  __shared__ __align__(16) unsigned char lA[128 * 128];
  __shared__ __align__(16) unsigned char lB[64 * 128];
  const int tid  = threadIdx.x;
  const int wave = tid >> 6;
  const int lane = tid & 63;
  int colb, rowb;
  swz8x64(colb, rowb);
  const int bm  = rowb * 128;
  const int bnp = colb;                  // col-pair group: cols [32bnp, 32bnp+32)
  const int wm  = wave * 64;

  floatx4 acc[4][4];
#pragma unroll
  for (int i = 0; i < 4; ++i)
#pragma unroll
    for (int j = 0; j < 4; ++j)
      acc[i][j] = (floatx4){0.f, 0.f, 0.f, 0.f};

  const int jj = lane >> 3;
  const int chunkoff = ((lane & 7) ^ jj) * 16;
  const unsigned char* gA = A + (size_t)(bm + jj) * K + chunkoff;
  const unsigned char* gB =
      W + (size_t)((wave ? 256 : 0) + 32 * bnp + jj) * K + chunkoff;

  const int q = lane >> 4;
  const int r = lane & 15;

  for (int k0 = 0; k0 < K; k0 += 128) {
    if (k0) __syncthreads();
#pragma unroll
    for (int ii = 0; ii < 8; ++ii) {
      const int i = 8 * wave + ii;
      gload_lds16(gA + (size_t)(8 * i) * K + k0, &lA[i * 1024]);
    }
#pragma unroll
    for (int ii = 0; ii < 4; ++ii) {
      gload_lds16(gB + (size_t)(8 * ii) * K + k0, &lB[(4 * wave + ii) * 1024]);
    }
    __syncthreads();

    int8v af[4], bfv[4];
#pragma unroll
    for (int t = 0; t < 4; ++t) af[t]  = read_frag8(lA, wm + t * 16 + r, q);
#pragma unroll
    for (int t = 0; t < 4; ++t) bfv[t] = read_frag8(lB, t * 16 + r, q);

#pragma unroll
    for (int i = 0; i < 4; ++i)
#pragma unroll
      for (int j = 0; j < 4; ++j)
        acc[i][j] = __builtin_amdgcn_mfma_scale_f32_16x16x128_f8f6f4(
            af[i], bfv[j], acc[i][j], 0, 0, 0, 0x7f7f7f7f, 0, 0x7f7f7f7f);
  }

  const int q4 = (lane >> 4) * 4;
  const int cc = lane & 15;
  float ssum[4][4];
#pragma unroll
  for (int i = 0; i < 4; ++i)
#pragma unroll
    for (int rr = 0; rr < 4; ++rr) ssum[i][rr] = 0.f;

#pragma unroll
  for (int i = 0; i < 4; ++i) {
    const int row0 = bm + wm + i * 16 + q4;
#pragma unroll
    for (int jjp = 0; jjp < 2; ++jjp) {
      const int cp = 32 * bnp + jjp * 16 + cc;
      const float bs = bias[cp];
      const float bt = bias[256 + cp];
#pragma unroll
      for (int rr = 0; rr < 4; ++rr) {
        const int row = row0 + rr;
        float sa = 0.1f * (acc[i][jjp][rr] + bs);
        float ta = 0.1f * (acc[i][jjp + 2][rr] + bt);
        float s  = 2.0f * tanhf(sa);
        float x2n = xst[(size_t)row * 512 + 256 + cp] * expf(s) + ta;
        if (LASTF) {
          outF[(size_t)row * 512 + 256 + cp] = x2n;
        } else {
          xbn[(size_t)row * C_ + D1_ + cp] = f2bf(x2n * scn[D1_ + cp] + offn[D1_ + cp]);
        }
        ssum[i][rr] += s;
      }
    }
  }

#pragma unroll
  for (int i = 0; i < 4; ++i)
#pragma unroll
    for (int rr = 0; rr < 4; ++rr) {
      float v = ssum[i][rr];
#pragma unroll
      for (int m = 1; m < 16; m <<= 1) v += __shfl_xor(v, m, 64);
      if (cc == 0) {
        const int row = bm + wm + i * 16 + q4 + rr;
        ldpart[(size_t)bnp * B_ + row] += v;
      }
    }
}

// scale[f][c] = 0.2*softplus(0.5*g); sumlog[f] = sum_c log(scale)
__global__ void scale_kernel(const float* __restrict__ g, float* __restrict__ sc,
                             float* __restrict__ sumlog) {
  const int f = blockIdx.x, t = threadIdx.x;
  __shared__ float red[256];
  float part = 0.f;
  for (int c = t; c < C_; c += 256) {
    float x  = 0.5f * g[f * C_ + c];
    float sp = log1pf(expf(x));
    float s  = 0.2f * sp;
    sc[f * C_ + c] = s;
    part += logf(s);
  }
  red[t] = part;
  __syncthreads();
  for (int o = 128; o > 0; o >>= 1) {
    if (t < o) red[t] += red[t + o];
    __syncthreads();
  }
  if (t == 0) sumlog[f] = red[0];
}

__global__ void cvt4_kernel(const float* __restrict__ s0, unsigned short* __restrict__ d0, int n0,
                            const float* __restrict__ s1, unsigned char* __restrict__ d1, int n1,
                            const float* __restrict__ s2, unsigned char* __restrict__ d2, int n2,
                            const float* __restrict__ s3, unsigned char* __restrict__ d3, int n3) {
  const int total4 = (n0 + n1 + n2 + n3) >> 2;
  for (int i = blockIdx.x * blockDim.x + threadIdx.x; i < total4;
       i += gridDim.x * blockDim.x) {
    int idx = i << 2;
    if (idx < n0) {
      float4 v = *(const float4*)(s0 + idx);
      ushort4 o;
      o.x = f2bf(v.x); o.y = f2bf(v.y); o.z = f2bf(v.z); o.w = f2bf(v.w);
      *(ushort4*)(d0 + idx) = o;
    } else {
      const float* s; unsigned char* d; int off;
      if (idx < n0 + n1)           { s = s1; d = d1; off = idx - n0; }
      else if (idx < n0 + n1 + n2) { s = s2; d = d2; off = idx - n0 - n1; }
      else                         { s = s3; d = d3; off = idx - n0 - n1 - n2; }
      *(unsigned int*)(d + off) = f2fp8x4(*(const float4*)(s + off));
    }
  }
}

// f=0: xb = bf16(z0*scale + off); also zero ldpart (8*B floats)
__global__ void prewp_kernel(const float* __restrict__ x, const float* __restrict__ sc,
                             const float* __restrict__ off, unsigned short* __restrict__ xb,
                             float* __restrict__ ldpart) {
  int i = blockIdx.x * blockDim.x + threadIdx.x;
  if (i < (8 * B_) / 4) *(float4*)(ldpart + i * 4) = (float4){0.f, 0.f, 0.f, 0.f};
  if (i >= (B_ * C_) / 4) return;
  int idx = i << 2;
  int c = idx & (C_ - 1);
  float4 v = *(const float4*)(x + idx);
  float4 s = *(const float4*)(sc + c);
  float4 o = *(const float4*)(off + c);
  ushort4 r;
  r.x = f2bf(v.x * s.x + o.x);
  r.y = f2bf(v.y * s.y + o.y);
  r.z = f2bf(v.z * s.z + o.z);
  r.w = f2bf(v.w * s.w + o.w);
  *(ushort4*)(xb + idx) = r;
}

// out_ld[row] = sum_nb ldpart[nb][row] + sum_f sumlog[f]
__global__ void final_ld_kernel(const float* __restrict__ ldpart,
                                const float* __restrict__ sumlog,
                                float* __restrict__ ldout) {
  int row = blockIdx.x * blockDim.x + threadIdx.x;
  if (row >= B_) return;
  float t = 0.f;
#pragma unroll
  for (int f = 0; f < F_; ++f) t += sumlog[f];
  float v = 0.f;
#pragma unroll
  for (int nb = 0; nb < 8; ++nb) v += ldpart[(size_t)nb * B_ + row];
  ldout[row] = v + t;
}

extern "C" void kernel_launch(void* const* d_in, const int* in_sizes, int n_in,
                              void* d_out, int out_size, void* d_ws, size_t ws_size,
                              hipStream_t stream) {
  const float* z0  = (const float*)d_in[0];
  const float* Wp  = (const float*)d_in[1];
  const float* g   = (const float*)d_in[2];
  const float* off = (const float*)d_in[3];
  const float* w0  = (const float*)d_in[4];
  const float* b0  = (const float*)d_in[5];
  const float* wh  = (const float*)d_in[6];
  const float* bh  = (const float*)d_in[7];
  const float* wo  = (const float*)d_in[8];
  const float* bo  = (const float*)d_in[9];
  float* out = (float*)d_out;

  char* ws = (char*)d_ws;
  size_t p = 0;
  auto alloc = [&](size_t bytes) -> void* {
    p = (p + 255) & ~(size_t)255;
    void* r = ws + p;
    p += bytes;
    return r;
  };
  float* sc           = (float*)alloc((size_t)F_ * C_ * 4);
  float* sumlog       = (float*)alloc((size_t)F_ * 4);
  float* ldpart       = (float*)alloc((size_t)8 * B_ * 4);
  float* xst          = (float*)alloc((size_t)B_ * C_ * 4);
  unsigned short* xbA = (unsigned short*)alloc((size_t)B_ * C_ * 2);
  unsigned short* xbB = (unsigned short*)alloc((size_t)B_ * C_ * 2);
  unsigned char* x1f8 = (unsigned char*)alloc((size_t)B_ * D1_);
  unsigned char* h1f8 = (unsigned char*)alloc((size_t)B_ * COUP_);
  unsigned char* h2f8 = (unsigned char*)alloc((size_t)B_ * COUP_);
  unsigned short* wpb = (unsigned short*)alloc((size_t)F_ * C_ * C_ * 2);
  unsigned char* w0f8 = (unsigned char*)alloc((size_t)F_ * COUP_ * D1_);
  unsigned char* whf8 = (unsigned char*)alloc((size_t)F_ * NBL_ * COUP_ * COUP_);
  unsigned char* wof8 = (unsigned char*)alloc((size_t)F_ * 2 * D2_ * COUP_);
  (void)ws_size; (void)in_sizes; (void)n_in; (void)out_size;

  scale_kernel<<<F_, 256, 0, stream>>>(g, sc, sumlog);

  cvt4_kernel<<<2048, 256, 0, stream>>>(
      Wp, wpb, F_ * C_ * C_,
      w0, w0f8, F_ * COUP_ * D1_,
      wh, whf8, F_ * NBL_ * COUP_ * COUP_,
      wo, wof8, F_ * 2 * D2_ * COUP_);

  prewp_kernel<<<(B_ * C_ / 4) / 256, 256, 0, stream>>>(z0, sc, off, xbA, ldpart);

  for (int f = 0; f < F_; ++f) {
    const int last = (f == F_ - 1);
    unsigned short* xbc = (f & 1) ? xbB : xbA;
    unsigned short* xbn = (f & 1) ? xbA : xbB;
    const float* scn  = sc  + (size_t)(f + 1) * C_;
    const float* offn = off + (size_t)(f + 1) * C_;

    if (!last) {
      gemm_wp<0><<<dim3(8, 64), 128, 0, stream>>>(
          xbc, wpb + (size_t)f * C_ * C_, xst, x1f8, scn, offn, xbn, B_, 512, 512);
    } else {
      gemm_wp<1><<<dim3(8, 64), 128, 0, stream>>>(
          xbc, wpb + (size_t)f * C_ * C_, out, x1f8, nullptr, nullptr, nullptr,
          B_, 512, 512);
    }

    gemm_f8<<<dim3(8, 64), 256, 0, stream>>>(
        x1f8, w0f8 + (size_t)f * COUP_ * D1_, b0 + (size_t)f * COUP_,
        h1f8, B_, COUP_, D1_);

    gemm_f8<<<dim3(8, 64), 256, 0, stream>>>(
        h1f8, whf8 + (size_t)(f * NBL_) * COUP_ * COUP_,
        bh + (size_t)(f * NBL_ + 0) * COUP_, h2f8, B_, COUP_, COUP_);

    gemm_f8<<<dim3(8, 64), 256, 0, stream>>>(
        h2f8, whf8 + (size_t)(f * NBL_ + 1) * COUP_ * COUP_,
        bh + (size_t)(f * NBL_ + 1) * COUP_, h1f8, B_, COUP_, COUP_);

    if (!last) {
      gemm_wo_couple<0><<<dim3(8, 64), 128, 0, stream>>>(
          h1f8, wof8 + (size_t)f * 2 * D2_ * COUP_, bo + (size_t)f * 2 * D2_,
          xst, nullptr, scn, offn, xbn, ldpart, B_, COUP_);
    } else {
      gemm_wo_couple<1><<<dim3(8, 64), 128, 0, stream>>>(
          h1f8, wof8 + (size_t)f * 2 * D2_ * COUP_, bo + (size_t)f * 2 * D2_,
          out, out, nullptr, nullptr, nullptr, ldpart, B_, COUP_);
    }
  }

  final_ld_kernel<<<B_ / 256, 256, 0, stream>>>(ldpart, sumlog, out + (size_t)B_ * C_);
}